// Round 1
// baseline (1326.035 us; speedup 1.0000x reference)
//
#include <hip/hip_runtime.h>

#define E_TOTAL   160000
#define NODES     10000
#define FDIM      128     // EDGE_FDIM
#define HDIM      128     // H_DIM
#define WN        1024    // WNUM = 4*16*16
#define CDIM      64      // 4*MUL
#define EPB       32      // edges per block
#define NTHR      256

static_assert(E_TOTAL % EPB == 0, "exact tiling assumed");

// Fused: edge gather + MLP(2 layers) + tensor product + scatter-add.
// Per block: 32 edges. LDS ~45 KB -> up to 3 blocks/CU (LDS-wise).
__global__ __launch_bounds__(NTHR)
void fused_edge_kernel(const float* __restrict__ x,
                       const int*   __restrict__ edge_index,
                       const float* __restrict__ edge_attr,
                       const float* __restrict__ edge_sh,
                       const float* __restrict__ fc_w1,
                       const float* __restrict__ fc_b1,
                       const float* __restrict__ fc_w2,
                       const float* __restrict__ fc_b2,
                       float*       __restrict__ out_acc,   // NODES*CDIM, pre-zeroed
                       int*         __restrict__ cnt)       // NODES, pre-zeroed
{
    __shared__ float attrT[FDIM][EPB + 1];           // +1 pad: conflict-free transpose
    __shared__ __align__(16) float hT[HDIM][EPB];    // rows 128B: aligned b128 reads
    __shared__ float g_a0 [EPB][16];   // x0*sh0          (path w00 -> out0)
    __shared__ float g_a1 [EPB][16];   // dot(x1,sh1)/sqrt3 (path w11 -> out0)
    __shared__ float g_x0 [EPB][16];   // x0              (path w01 -> out1, *sh1[m])
    __shared__ float g_x1s[EPB][48];   // x1*sh0          (path w10 -> out1)
    __shared__ float g_sh1[EPB][3];
    __shared__ int   g_dst[EPB];

    const int tid = threadIdx.x;
    const int e0  = blockIdx.x * EPB;

    // ---- stage edge_attr (transposed: attrT[i][e]) ----
    for (int t = tid; t < EPB * (FDIM / 4); t += NTHR) {
        const int e  = t >> 5;        // FDIM/4 == 32 float4 per row
        const int i4 = t & 31;
        const float4 v = ((const float4*)(edge_attr + (size_t)(e0 + e) * FDIM))[i4];
        attrT[i4 * 4 + 0][e] = v.x;
        attrT[i4 * 4 + 1][e] = v.y;
        attrT[i4 * 4 + 2][e] = v.z;
        attrT[i4 * 4 + 3][e] = v.w;
    }

    // ---- per-edge geometry factors ----
    if (tid < EPB) {
        const int ge = e0 + tid;
        const int s  = edge_index[ge];             // row 0: src
        const int d  = edge_index[E_TOTAL + ge];   // row 1: dst
        g_dst[tid] = d;
        atomicAdd(&cnt[d], 1);
        float xe[CDIM];
        const float4* xp = (const float4*)(x + (size_t)s * CDIM);
        #pragma unroll
        for (int t4 = 0; t4 < CDIM / 4; ++t4) {
            const float4 v = xp[t4];
            xe[t4*4+0] = v.x; xe[t4*4+1] = v.y; xe[t4*4+2] = v.z; xe[t4*4+3] = v.w;
        }
        const float sh0 = edge_sh[(size_t)ge*4 + 0];
        const float s1x = edge_sh[(size_t)ge*4 + 1];
        const float s1y = edge_sh[(size_t)ge*4 + 2];
        const float s1z = edge_sh[(size_t)ge*4 + 3];
        g_sh1[tid][0] = s1x; g_sh1[tid][1] = s1y; g_sh1[tid][2] = s1z;
        const float inv_sqrt3 = 0.57735026918962576f;
        #pragma unroll
        for (int u = 0; u < 16; ++u) {
            const float x0u = xe[u];
            g_x0[tid][u] = x0u;
            g_a0[tid][u] = x0u * sh0;
            const float xa = xe[16 + u*3 + 0];
            const float xb = xe[16 + u*3 + 1];
            const float xc = xe[16 + u*3 + 2];
            g_x1s[tid][u*3+0] = xa * sh0;
            g_x1s[tid][u*3+1] = xb * sh0;
            g_x1s[tid][u*3+2] = xc * sh0;
            g_a1[tid][u] = (xa*s1x + xb*s1y + xc*s1z) * inv_sqrt3;
        }
    }
    __syncthreads();

    // ---- GEMM1: h = relu(attr @ W1 + b1) -> hT[j][e] ----
    {
        const int e  = tid & 31;
        const int j0 = (tid >> 5) * 16;
        float acc[16];
        #pragma unroll
        for (int c4 = 0; c4 < 4; ++c4) {
            const float4 b = ((const float4*)(fc_b1 + j0))[c4];
            acc[c4*4+0] = b.x; acc[c4*4+1] = b.y; acc[c4*4+2] = b.z; acc[c4*4+3] = b.w;
        }
        #pragma unroll 4
        for (int i = 0; i < FDIM; ++i) {
            const float av = attrT[i][e];
            const float4* wp = (const float4*)(fc_w1 + (size_t)i * HDIM + j0);
            #pragma unroll
            for (int c4 = 0; c4 < 4; ++c4) {
                const float4 w = wp[c4];
                acc[c4*4+0] = fmaf(av, w.x, acc[c4*4+0]);
                acc[c4*4+1] = fmaf(av, w.y, acc[c4*4+1]);
                acc[c4*4+2] = fmaf(av, w.z, acc[c4*4+2]);
                acc[c4*4+3] = fmaf(av, w.w, acc[c4*4+3]);
            }
        }
        #pragma unroll
        for (int c = 0; c < 16; ++c) hT[j0 + c][e] = fmaxf(acc[c], 0.f);
    }
    __syncthreads();

    // ---- GEMM2 (w = h@W2 + b2, streamed from L2) + TP fold ----
    // thread -> 4 edges (eb..eb+3) x k-quad q. k = kp*256 + {0,128} + q*4 + i
    //   p = kp (path), u = q>>2 (+8 for upper half), wi = (q&3)*4 + i
    const int q  = tid & 31;
    const int eb = (tid >> 5) * 4;
    const int r  = q & 3;
    const int ua = q >> 2;        // u for lower 128-half (kp*16 wraps mod 16)
    const int ub = ua + 8;        // u for upper 128-half

    float o0[4][4];               // out0 partials [e][i], wi = r*4+i
    float o1[4][4][3];            // out1 partials [e][i][m]
    #pragma unroll
    for (int e = 0; e < 4; ++e)
        #pragma unroll
        for (int i = 0; i < 4; ++i) {
            o0[e][i] = 0.f;
            o1[e][i][0] = 0.f; o1[e][i][1] = 0.f; o1[e][i][2] = 0.f;
        }
    float sh1c[4][3];
    #pragma unroll
    for (int e = 0; e < 4; ++e) {
        sh1c[e][0] = g_sh1[eb+e][0];
        sh1c[e][1] = g_sh1[eb+e][1];
        sh1c[e][2] = g_sh1[eb+e][2];
    }

    #pragma unroll
    for (int kp = 0; kp < 4; ++kp) {
        const int ka = kp * 256 + q * 4;
        const int kb = ka + 128;
        float Sa[4][4], Sb[4][4];
        #pragma unroll
        for (int e = 0; e < 4; ++e)
            #pragma unroll
            for (int i = 0; i < 4; ++i) { Sa[e][i] = 0.f; Sb[e][i] = 0.f; }

        const float* w2a = fc_w2 + ka;
        const float* w2b = fc_w2 + kb;
        #pragma unroll 2
        for (int j = 0; j < HDIM; ++j) {
            const float4 h4 = *(const float4*)(&hT[j][eb]);
            const float4 wa = *(const float4*)(w2a + (size_t)j * WN);
            const float4 wb = *(const float4*)(w2b + (size_t)j * WN);
            const float hv[4]  = {h4.x, h4.y, h4.z, h4.w};
            const float wav[4] = {wa.x, wa.y, wa.z, wa.w};
            const float wbv[4] = {wb.x, wb.y, wb.z, wb.w};
            #pragma unroll
            for (int e = 0; e < 4; ++e)
                #pragma unroll
                for (int i = 0; i < 4; ++i) {
                    Sa[e][i] = fmaf(hv[e], wav[i], Sa[e][i]);
                    Sb[e][i] = fmaf(hv[e], wbv[i], Sb[e][i]);
                }
        }

        // add bias -> full w values for this thread's 8 k's per edge
        const float4 b2a4 = *(const float4*)(fc_b2 + ka);
        const float4 b2b4 = *(const float4*)(fc_b2 + kb);
        const float b2av[4] = {b2a4.x, b2a4.y, b2a4.z, b2a4.w};
        const float b2bv[4] = {b2b4.x, b2b4.y, b2b4.z, b2b4.w};
        float wfa[4][4], wfb[4][4];
        #pragma unroll
        for (int e = 0; e < 4; ++e)
            #pragma unroll
            for (int i = 0; i < 4; ++i) {
                wfa[e][i] = Sa[e][i] + b2av[i];
                wfb[e][i] = Sb[e][i] + b2bv[i];
            }

        if (kp == 0) {            // w00: out0 += (x0*sh0)[u] * w
            #pragma unroll
            for (int e = 0; e < 4; ++e) {
                const float aa = g_a0[eb+e][ua];
                const float ab = g_a0[eb+e][ub];
                #pragma unroll
                for (int i = 0; i < 4; ++i)
                    o0[e][i] = fmaf(aa, wfa[e][i], fmaf(ab, wfb[e][i], o0[e][i]));
            }
        } else if (kp == 1) {     // w01: out1[wi][m] += x0[u]*w*sh1[m]
            #pragma unroll
            for (int e = 0; e < 4; ++e) {
                const float ta = g_x0[eb+e][ua];
                const float tb = g_x0[eb+e][ub];
                #pragma unroll
                for (int i = 0; i < 4; ++i) {
                    const float t = ta * wfa[e][i] + tb * wfb[e][i];
                    #pragma unroll
                    for (int m = 0; m < 3; ++m)
                        o1[e][i][m] = fmaf(t, sh1c[e][m], o1[e][i][m]);
                }
            }
        } else if (kp == 2) {     // w10: out1[wi][m] += (x1*sh0)[u][m]*w
            #pragma unroll
            for (int e = 0; e < 4; ++e) {
                const float xa0 = g_x1s[eb+e][ua*3+0];
                const float xa1 = g_x1s[eb+e][ua*3+1];
                const float xa2 = g_x1s[eb+e][ua*3+2];
                const float xb0 = g_x1s[eb+e][ub*3+0];
                const float xb1 = g_x1s[eb+e][ub*3+1];
                const float xb2 = g_x1s[eb+e][ub*3+2];
                #pragma unroll
                for (int i = 0; i < 4; ++i) {
                    o1[e][i][0] = fmaf(xa0, wfa[e][i], fmaf(xb0, wfb[e][i], o1[e][i][0]));
                    o1[e][i][1] = fmaf(xa1, wfa[e][i], fmaf(xb1, wfb[e][i], o1[e][i][1]));
                    o1[e][i][2] = fmaf(xa2, wfa[e][i], fmaf(xb2, wfb[e][i], o1[e][i][2]));
                }
            }
        } else {                  // kp==3, w11: out0 += (dot/sqrt3)[u] * w
            #pragma unroll
            for (int e = 0; e < 4; ++e) {
                const float aa = g_a1[eb+e][ua];
                const float ab = g_a1[eb+e][ub];
                #pragma unroll
                for (int i = 0; i < 4; ++i)
                    o0[e][i] = fmaf(aa, wfa[e][i], fmaf(ab, wfb[e][i], o0[e][i]));
            }
        }
    }

    // ---- reduce across the 8 u-threads (tid bits 2..4) via xor-butterfly ----
    #pragma unroll
    for (int mask = 4; mask <= 16; mask <<= 1) {
        #pragma unroll
        for (int e = 0; e < 4; ++e)
            #pragma unroll
            for (int i = 0; i < 4; ++i) {
                o0[e][i] += __shfl_xor(o0[e][i], mask);
                o1[e][i][0] += __shfl_xor(o1[e][i][0], mask);
                o1[e][i][1] += __shfl_xor(o1[e][i][1], mask);
                o1[e][i][2] += __shfl_xor(o1[e][i][2], mask);
            }
    }

    // ---- scatter-add (lanes with q>>2 == 0) ----
    if ((tid & 28) == 0) {
        const float alpha = 0.17677669529663689f;   // 1/sqrt(2*MUL)
        #pragma unroll
        for (int e = 0; e < 4; ++e) {
            const int d = g_dst[eb + e];
            float* op = out_acc + (size_t)d * CDIM;
            #pragma unroll
            for (int i = 0; i < 4; ++i) {
                const int wi = r * 4 + i;
                unsafeAtomicAdd(&op[wi], alpha * o0[e][i]);
                #pragma unroll
                for (int m = 0; m < 3; ++m)
                    unsafeAtomicAdd(&op[16 + wi*3 + m], alpha * o1[e][i][m]);
            }
        }
    }
}

__global__ void finalize_kernel(const float* __restrict__ x,
                                const int*   __restrict__ cnt,
                                float*       __restrict__ out)
{
    const int idx = blockIdx.x * blockDim.x + threadIdx.x;
    if (idx < NODES * CDIM) {
        const int n = idx >> 6;
        const float c = (float)(cnt[n] > 1 ? cnt[n] : 1);
        out[idx] = out[idx] / c + x[idx];
    }
}

extern "C" void kernel_launch(void* const* d_in, const int* in_sizes, int n_in,
                              void* d_out, int out_size, void* d_ws, size_t ws_size,
                              hipStream_t stream) {
    (void)in_sizes; (void)n_in; (void)out_size; (void)ws_size;
    const float* x         = (const float*)d_in[0];
    const int*   edge_index= (const int*)  d_in[1];
    const float* edge_attr = (const float*)d_in[2];
    const float* edge_sh   = (const float*)d_in[3];
    const float* fc_w1     = (const float*)d_in[4];
    const float* fc_b1     = (const float*)d_in[5];
    const float* fc_w2     = (const float*)d_in[6];
    const float* fc_b2     = (const float*)d_in[7];
    float* out = (float*)d_out;
    int*   cnt = (int*)d_ws;

    hipMemsetAsync(out, 0, (size_t)NODES * CDIM * sizeof(float), stream);
    hipMemsetAsync(cnt, 0, (size_t)NODES * sizeof(int), stream);

    fused_edge_kernel<<<E_TOTAL / EPB, NTHR, 0, stream>>>(
        x, edge_index, edge_attr, edge_sh, fc_w1, fc_b1, fc_w2, fc_b2, out, cnt);
    finalize_kernel<<<(NODES * CDIM + NTHR - 1) / NTHR, NTHR, 0, stream>>>(x, cnt, out);
}

// Round 2
// 396.909 us; speedup vs baseline: 3.3409x; 3.3409x over previous
//
#include <hip/hip_runtime.h>
#include <stdint.h>

#define E_TOTAL 160000
#define NODES   10000
#define FDIM    128
#define HDIM    128
#define WN      1024
#define CDIM    64
#define EPB     64
#define NTHR    256

typedef __bf16 bf16x8 __attribute__((ext_vector_type(8)));
typedef float  f32x4  __attribute__((ext_vector_type(4)));

#define MFMA16(a,b,c) __builtin_amdgcn_mfma_f32_16x16x32_bf16(a,b,c,0,0,0)

// ws layout (bytes):
//   [0,        524288)  W2B : 64 tiles x 8KB, split-bf16, B-fragment layout
//   [524288,   589824)  W1B : 8 tiles x 8KB
//   [589824,  ...    )  cnt : NODES int
#define WS_W1B (512*1024)
#define WS_CNT (576*1024)

__device__ __forceinline__ void async16(const void* g, void* l) {
    __builtin_amdgcn_global_load_lds(
        (const __attribute__((address_space(1))) uint32_t*)g,
        (__attribute__((address_space(3))) uint32_t*)l, 16, 0, 0);
}

// Split W[k][n] (row-major, K=128 rows, N cols) into hi/lo bf16 packed as
// MFMA B-fragments: [tile][ks][term][lane][8 bf16], 8KB per 16-col tile.
// Fragment: lane holds n = tile*16 + (lane&15), k = ks*32 + (lane>>4)*8 + j.
__global__ void prep_split_kernel(const float* __restrict__ W, __bf16* __restrict__ outB,
                                  int N, int ntiles) {
    const int gid  = blockIdx.x * 256 + threadIdx.x;
    const int lane = gid & 63;
    const int ks   = (gid >> 6) & 3;
    const int tile = gid >> 8;
    if (tile >= ntiles) return;
    const int n  = tile * 16 + (lane & 15);
    const int k0 = ks * 32 + (lane >> 4) * 8;
    bf16x8 hi, lo;
    #pragma unroll
    for (int j = 0; j < 8; ++j) {
        const float v = W[(size_t)(k0 + j) * N + n];
        const __bf16 h = (__bf16)v;
        hi[j] = h;
        lo[j] = (__bf16)(v - (float)h);
    }
    const size_t base = ((size_t)(tile * 4 + ks) * 2 * 64 + lane) * 8;
    *(bf16x8*)(outB + base)          = hi;     // term 0
    *(bf16x8*)(outB + base + 64 * 8) = lo;     // term 1
}

__global__ __launch_bounds__(NTHR, 2)
void fused_edge_kernel(const float* __restrict__ x,
                       const int*   __restrict__ edge_index,
                       const float* __restrict__ edge_attr,
                       const float* __restrict__ edge_sh,
                       const float* __restrict__ fc_b1,
                       const float* __restrict__ fc_b2,
                       const __bf16* __restrict__ W1B,
                       const __bf16* __restrict__ W2B,
                       float* __restrict__ out_acc,
                       int*   __restrict__ cnt)
{
    __shared__ float s_fA0[16][EPB];      // alpha*sh0*x0[u]        (p=0 -> out0)
    __shared__ float s_fA1[16][EPB];      // alpha/sqrt3*dot(x1,sh1) (p=3 -> out0)
    __shared__ float s_fX0[16][EPB];      // alpha*x0[u]            (p=1 -> out1*sh1)
    __shared__ float s_fX1[3][16][EPB];   // alpha*sh0*x1[u][m]     (p=2 -> out1)
    __shared__ float4 s_sh[EPB];          // (sh1x, sh1y, sh1z, sh0)
    __shared__ int    s_dst[EPB];
    __shared__ __align__(16) char s_pool[50176];
    // phase1: h_buf = s_pool[0..33792), B1 dbuf = s_pool[33792..50176)
    // phase3: B2 dbuf = s_pool[0..32768)

    const int tid  = threadIdx.x;
    const int w    = tid >> 6;
    const int lane = tid & 63;
    const int quad = lane >> 4;
    const int li   = lane & 15;
    const int e0   = blockIdx.x * EPB;

    // ---------------- phase 0: per-edge geometry factors ----------------
    {
        const int e  = tid & 63;
        const int up = w * 4;                      // wave w computes u in [up, up+4)
        const int ge = e0 + e;
        const int src = edge_index[ge];
        const float4 sh4 = *(const float4*)(edge_sh + (size_t)ge * 4);
        if (tid < EPB) {
            const int d = edge_index[E_TOTAL + ge];
            s_dst[e] = d;
            atomicAdd(&cnt[d], 1);
            s_sh[e] = make_float4(sh4.y, sh4.z, sh4.w, sh4.x);
        }
        const float* xp = x + (size_t)src * CDIM;
        const float4 x0v = *(const float4*)(xp + up);
        const float4 xa  = *(const float4*)(xp + 16 + up * 3);
        const float4 xb  = *(const float4*)(xp + 16 + up * 3 + 4);
        const float4 xc  = *(const float4*)(xp + 16 + up * 3 + 8);
        const float x1v[4][3] = {
            {xa.x, xa.y, xa.z}, {xa.w, xb.x, xb.y},
            {xb.z, xb.w, xc.x}, {xc.y, xc.z, xc.w}};
        const float x0a[4] = {x0v.x, x0v.y, x0v.z, x0v.w};
        const float alpha = 0.17677669529663689f;        // 1/sqrt(2*MUL)
        const float ai3   = alpha * 0.57735026918962576f;
        const float sh0   = sh4.x;
        #pragma unroll
        for (int j = 0; j < 4; ++j) {
            const int u = up + j;
            s_fX0[u][e] = alpha * x0a[j];
            s_fA0[u][e] = alpha * sh0 * x0a[j];
            s_fA1[u][e] = ai3 * (x1v[j][0]*sh4.y + x1v[j][1]*sh4.z + x1v[j][2]*sh4.w);
            s_fX1[0][u][e] = alpha * sh0 * x1v[j][0];
            s_fX1[1][u][e] = alpha * sh0 * x1v[j][1];
            s_fX1[2][u][e] = alpha * sh0 * x1v[j][2];
        }
    }

    // ---- A1 fragments: edge_attr split-bf16, direct global->reg ----
    // A[m=li][k=ks*32+quad*8+j], edge m of this wave = e0 + w*16 + li
    bf16x8 A1h[4], A1l[4];
    {
        const float* ap = edge_attr + (size_t)(e0 + w * 16 + li) * FDIM + quad * 8;
        #pragma unroll
        for (int ks = 0; ks < 4; ++ks) {
            const float4 f0 = *(const float4*)(ap + ks * 32);
            const float4 f1 = *(const float4*)(ap + ks * 32 + 4);
            const float fv[8] = {f0.x, f0.y, f0.z, f0.w, f1.x, f1.y, f1.z, f1.w};
            #pragma unroll
            for (int j = 0; j < 8; ++j) {
                const __bf16 h = (__bf16)fv[j];
                A1h[ks][j] = h;
                A1l[ks][j] = (__bf16)(fv[j] - (float)h);
            }
        }
    }

    float* h_buf = (float*)s_pool;          // [64 e][132] fp32 (pad 4 -> 16B-aligned rows)
    char*  B1    = s_pool + 33792;

    // ---------------- phase 1: GEMM1 h = relu(attr @ W1 + b1) ----------------
    {
        const char* g0 = (const char*)W1B;
        // stage nt=0
        async16(g0 + tid * 16, B1 + tid * 16);
        async16(g0 + tid * 16 + 4096, B1 + tid * 16 + 4096);
        #pragma unroll 1
        for (int nt = 0; nt < 8; ++nt) {
            __syncthreads();
            if (nt + 1 < 8) {
                const char* g = g0 + (nt + 1) * 8192 + tid * 16;
                char* l = B1 + ((nt + 1) & 1) * 8192 + tid * 16;
                async16(g, l);
                async16(g + 4096, l + 4096);
            }
            const char* bb = B1 + (nt & 1) * 8192;
            f32x4 acc = {0.f, 0.f, 0.f, 0.f};
            #pragma unroll
            for (int ks = 0; ks < 4; ++ks) {
                const bf16x8 bh = *(const bf16x8*)(bb + ((ks * 2 + 0) * 64 + lane) * 16);
                const bf16x8 bl = *(const bf16x8*)(bb + ((ks * 2 + 1) * 64 + lane) * 16);
                acc = MFMA16(A1h[ks], bh, acc);
                acc = MFMA16(A1h[ks], bl, acc);
                acc = MFMA16(A1l[ks], bh, acc);
            }
            const float b1v = fc_b1[nt * 16 + li];
            #pragma unroll
            for (int r = 0; r < 4; ++r)
                h_buf[(w * 16 + quad * 4 + r) * 132 + nt * 16 + li] = fmaxf(acc[r] + b1v, 0.f);
        }
    }

    // ---------------- phase 2: h -> A2 fragments (own-wave LDS transpose) ----------------
    bf16x8 A2h[4], A2l[4];
    #pragma unroll
    for (int ks = 0; ks < 4; ++ks) {
        const float* hp = h_buf + (w * 16 + li) * 132 + ks * 32 + quad * 8;
        const float4 f0 = *(const float4*)(hp);
        const float4 f1 = *(const float4*)(hp + 4);
        const float fv[8] = {f0.x, f0.y, f0.z, f0.w, f1.x, f1.y, f1.z, f1.w};
        #pragma unroll
        for (int j = 0; j < 8; ++j) {
            const __bf16 h = (__bf16)fv[j];
            A2h[ks][j] = h;
            A2l[ks][j] = (__bf16)(fv[j] - (float)h);
        }
    }
    // sh1 for this lane's 4 C-rows (edges eb..eb+3)
    const int eb = w * 16 + quad * 4;
    float s1c[3][4];
    #pragma unroll
    for (int r = 0; r < 4; ++r) {
        const float4 t = s_sh[eb + r];
        s1c[0][r] = t.x; s1c[1][r] = t.y; s1c[2][r] = t.z;
    }
    __syncthreads();   // h_buf dead -> region reused for B2 staging

    // ---------------- phase 3: GEMM2 + TP fold ----------------
    char* B2 = s_pool;
    f32x4 o0  = {0.f, 0.f, 0.f, 0.f};
    f32x4 o1a = {0.f, 0.f, 0.f, 0.f};
    f32x4 o1b = {0.f, 0.f, 0.f, 0.f};
    f32x4 o1c = {0.f, 0.f, 0.f, 0.f};

    {   // stage chunk 0 (2 tiles = 16KB)
        const char* g = (const char*)W2B + tid * 16;
        char* l = B2 + tid * 16;
        #pragma unroll
        for (int i = 0; i < 4; ++i) async16(g + i * 4096, l + i * 4096);
    }
    #pragma unroll 1
    for (int c = 0; c < 32; ++c) {
        __syncthreads();
        if (c + 1 < 32) {
            const char* g = (const char*)W2B + (size_t)(c + 1) * 16384 + tid * 16;
            char* l = B2 + ((c + 1) & 1) * 16384 + tid * 16;
            #pragma unroll
            for (int i = 0; i < 4; ++i) async16(g + i * 4096, l + i * 4096);
        }
        const char* cb = B2 + (c & 1) * 16384;
        #pragma unroll
        for (int tt = 0; tt < 2; ++tt) {
            const int t = c * 2 + tt;        // k-tile: k = t*16 + wi = p*256 + u*16 + wi
            const int p = t >> 4;
            const int u = t & 15;
            const float b2v = fc_b2[t * 16 + li];
            const char* bb = cb + tt * 8192;
            f32x4 acc = {b2v, b2v, b2v, b2v};
            #pragma unroll
            for (int ks = 0; ks < 4; ++ks) {
                const bf16x8 bh = *(const bf16x8*)(bb + ((ks * 2 + 0) * 64 + lane) * 16);
                const bf16x8 bl = *(const bf16x8*)(bb + ((ks * 2 + 1) * 64 + lane) * 16);
                acc = MFMA16(A2h[ks], bh, acc);
                acc = MFMA16(A2h[ks], bl, acc);
                acc = MFMA16(A2l[ks], bh, acc);
            }
            // fold: C rows are edges eb..eb+3, col is wi = li; (p,u) tile-constant
            if (p == 0) {
                const float4 fv = *(const float4*)&s_fA0[u][eb];
                const float f[4] = {fv.x, fv.y, fv.z, fv.w};
                #pragma unroll
                for (int r = 0; r < 4; ++r) o0[r] += f[r] * acc[r];
            } else if (p == 1) {
                const float4 fv = *(const float4*)&s_fX0[u][eb];
                const float f[4] = {fv.x, fv.y, fv.z, fv.w};
                #pragma unroll
                for (int r = 0; r < 4; ++r) {
                    const float tmp = f[r] * acc[r];
                    o1a[r] += tmp * s1c[0][r];
                    o1b[r] += tmp * s1c[1][r];
                    o1c[r] += tmp * s1c[2][r];
                }
            } else if (p == 2) {
                const float4 f0v = *(const float4*)&s_fX1[0][u][eb];
                const float4 f1v = *(const float4*)&s_fX1[1][u][eb];
                const float4 f2v = *(const float4*)&s_fX1[2][u][eb];
                const float fa[4] = {f0v.x, f0v.y, f0v.z, f0v.w};
                const float fb[4] = {f1v.x, f1v.y, f1v.z, f1v.w};
                const float fc[4] = {f2v.x, f2v.y, f2v.z, f2v.w};
                #pragma unroll
                for (int r = 0; r < 4; ++r) {
                    o1a[r] += fa[r] * acc[r];
                    o1b[r] += fb[r] * acc[r];
                    o1c[r] += fc[r] * acc[r];
                }
            } else {
                const float4 fv = *(const float4*)&s_fA1[u][eb];
                const float f[4] = {fv.x, fv.y, fv.z, fv.w};
                #pragma unroll
                for (int r = 0; r < 4; ++r) o0[r] += f[r] * acc[r];
            }
        }
    }

    // ---------------- epilogue: scatter-add ----------------
    #pragma unroll
    for (int r = 0; r < 4; ++r) {
        const int d = s_dst[eb + r];
        float* op = out_acc + (size_t)d * CDIM;
        unsafeAtomicAdd(&op[li], o0[r]);
        unsafeAtomicAdd(&op[16 + li * 3 + 0], o1a[r]);
        unsafeAtomicAdd(&op[16 + li * 3 + 1], o1b[r]);
        unsafeAtomicAdd(&op[16 + li * 3 + 2], o1c[r]);
    }
}

__global__ void finalize_kernel(const float* __restrict__ x,
                                const int*   __restrict__ cnt,
                                float*       __restrict__ out)
{
    const int idx = blockIdx.x * blockDim.x + threadIdx.x;
    if (idx < NODES * CDIM) {
        const int n = idx >> 6;
        const float c = (float)(cnt[n] > 1 ? cnt[n] : 1);
        out[idx] = out[idx] / c + x[idx];
    }
}

extern "C" void kernel_launch(void* const* d_in, const int* in_sizes, int n_in,
                              void* d_out, int out_size, void* d_ws, size_t ws_size,
                              hipStream_t stream) {
    (void)in_sizes; (void)n_in; (void)out_size; (void)ws_size;
    const float* x          = (const float*)d_in[0];
    const int*   edge_index = (const int*)  d_in[1];
    const float* edge_attr  = (const float*)d_in[2];
    const float* edge_sh    = (const float*)d_in[3];
    const float* fc_w1      = (const float*)d_in[4];
    const float* fc_b1      = (const float*)d_in[5];
    const float* fc_w2      = (const float*)d_in[6];
    const float* fc_b2      = (const float*)d_in[7];
    float*  out = (float*)d_out;
    __bf16* W2B = (__bf16*)d_ws;
    __bf16* W1B = (__bf16*)((char*)d_ws + WS_W1B);
    int*    cnt = (int*)((char*)d_ws + WS_CNT);

    hipMemsetAsync(out, 0, (size_t)NODES * CDIM * sizeof(float), stream);
    hipMemsetAsync(cnt, 0, (size_t)NODES * sizeof(int), stream);

    prep_split_kernel<<<8, 256, 0, stream>>>(fc_w1, W1B, HDIM, 8);
    prep_split_kernel<<<64, 256, 0, stream>>>(fc_w2, W2B, WN, 64);

    fused_edge_kernel<<<E_TOTAL / EPB, NTHR, 0, stream>>>(
        x, edge_index, edge_attr, edge_sh, fc_b1, fc_b2, W1B, W2B, out, cnt);
    finalize_kernel<<<(NODES * CDIM + NTHR - 1) / NTHR, NTHR, 0, stream>>>(x, cnt, out);
}

// Round 3
// 377.007 us; speedup vs baseline: 3.5173x; 1.0528x over previous
//
#include <hip/hip_runtime.h>
#include <stdint.h>

#define E_TOTAL 160000
#define NODES   10000
#define FDIM    128
#define HDIM    128
#define WN      1024
#define CDIM    64
#define EPB     64
#define NTHR    256

typedef __bf16 bf16x8 __attribute__((ext_vector_type(8)));
typedef float  f32x4  __attribute__((ext_vector_type(4)));

#define MFMA16(a,b,c) __builtin_amdgcn_mfma_f32_16x16x32_bf16(a,b,c,0,0,0)

// ws layout: [0, 512K) W2B split-bf16 B-frags ; [512K, 576K) W1B ; [576K, +40K) cnt
#define WS_W1B (512*1024)
#define WS_CNT (576*1024)

// ---------- prep: split W1/W2 to bf16 hi/lo B-fragments + zero out/cnt ----------
// Fragment layout: [tile][ks][term][lane][8 bf16]; lane holds n = tile*16 + (lane&15),
// k = ks*32 + (lane>>4)*8 + j.  One 256-thr block per tile (4 ks x 64 lanes).
__global__ void prep_kernel(const float* __restrict__ W1, const float* __restrict__ W2,
                            __bf16* __restrict__ W1B, __bf16* __restrict__ W2B,
                            float* __restrict__ out_acc, int* __restrict__ cnt) {
    const int b   = blockIdx.x;
    const int tid = threadIdx.x;
    if (b < 72) {
        const float* W = (b < 64) ? W2 : W1;
        __bf16* outB   = (b < 64) ? W2B : W1B;
        const int N    = (b < 64) ? WN : HDIM;
        const int tile = (b < 64) ? b : (b - 64);
        const int lane = tid & 63;
        const int ks   = tid >> 6;
        const int n  = tile * 16 + (lane & 15);
        const int k0 = ks * 32 + (lane >> 4) * 8;
        bf16x8 hi, lo;
        #pragma unroll
        for (int j = 0; j < 8; ++j) {
            const float v = W[(size_t)(k0 + j) * N + n];
            const __bf16 h = (__bf16)v;
            hi[j] = h;
            lo[j] = (__bf16)(v - (float)h);
        }
        const size_t base = ((size_t)(tile * 4 + ks) * 2 * 64 + lane) * 8;
        *(bf16x8*)(outB + base)       = hi;
        *(bf16x8*)(outB + base + 512) = lo;
    } else {
        const int zt = (b - 72) * NTHR + tid;            // 8 blocks x 256 = 2048 threads
        const float4 z4 = make_float4(0.f, 0.f, 0.f, 0.f);
        for (int i = zt; i < NODES * CDIM / 4; i += 8 * NTHR) ((float4*)out_acc)[i] = z4;
        for (int i = zt; i < NODES; i += 8 * NTHR) cnt[i] = 0;
    }
}

// ---------- fused: gather + MLP + tensor product + scatter ----------
// Per block: 64 edges. Wave w = (th = w>>1, kh = w&1):
//   GEMM2: wave covers tiles [th*32, th*32+32) x K-half [kh*64, kh*64+64) for ALL 64 edges.
//   K-partial sums are valid because the TP fold is linear in acc; bias added by kh==0 only.
// B fragments read straight from L2 (no LDS staging, no K-loop barriers), dbuf in regs.
__global__ __launch_bounds__(NTHR, 2)
void fused_edge_kernel(const float* __restrict__ x,
                       const int*   __restrict__ edge_index,
                       const float* __restrict__ edge_attr,
                       const float* __restrict__ edge_sh,
                       const float* __restrict__ fc_b1,
                       const float* __restrict__ fc_b2,
                       const __bf16* __restrict__ W1B,
                       const __bf16* __restrict__ W2B,
                       float* __restrict__ out_acc,
                       int*   __restrict__ cnt)
{
    // fold factors [8][u][e]: 0:a*sh0*x0 (p0) | 1..3:a*x0*sh1_m (p1) | 4..6:a*sh0*x1_m (p2) | 7:a/sqrt3*dot (p3)
    __shared__ float s_f[8][16][EPB];                  // 32 KB
    __shared__ __align__(16) float s_hb[64 * 132];     // 33.8 KB: attr -> h -> red (pad 132)
    __shared__ int s_dst[EPB];

    const int tid  = threadIdx.x;
    const int w    = tid >> 6;
    const int th   = w >> 1;
    const int kh   = w & 1;
    const int lane = tid & 63;
    const int quad = lane >> 4;
    const int li   = lane & 15;
    const int e0   = blockIdx.x * EPB;

    // ---- phase 0a: geometry factors (wave w computes u in [w*4, w*4+4) for all 64 edges) ----
    {
        const int e  = lane;
        const int up = w * 4;
        const int ge = e0 + e;
        const int src = edge_index[ge];
        const float4 sh4 = *(const float4*)(edge_sh + (size_t)ge * 4);
        if (tid < EPB) {
            const int d = edge_index[E_TOTAL + ge];
            s_dst[e] = d;
            atomicAdd(&cnt[d], 1);
        }
        const float* xp = x + (size_t)src * CDIM;
        const float4 x0v = *(const float4*)(xp + up);
        const float4 xa  = *(const float4*)(xp + 16 + up * 3);
        const float4 xb  = *(const float4*)(xp + 16 + up * 3 + 4);
        const float4 xc  = *(const float4*)(xp + 16 + up * 3 + 8);
        const float x1v[4][3] = {
            {xa.x, xa.y, xa.z}, {xa.w, xb.x, xb.y},
            {xb.z, xb.w, xc.x}, {xc.y, xc.z, xc.w}};
        const float x0a[4] = {x0v.x, x0v.y, x0v.z, x0v.w};
        const float alpha = 0.17677669529663689f;           // 1/sqrt(2*MUL)
        const float ai3   = alpha * 0.57735026918962576f;   // alpha/sqrt(3)
        const float sh0 = sh4.x, s1x = sh4.y, s1y = sh4.z, s1z = sh4.w;
        #pragma unroll
        for (int j = 0; j < 4; ++j) {
            const int u = up + j;
            const float x0u = x0a[j];
            s_f[0][u][e] = alpha * sh0 * x0u;
            s_f[1][u][e] = alpha * x0u * s1x;
            s_f[2][u][e] = alpha * x0u * s1y;
            s_f[3][u][e] = alpha * x0u * s1z;
            s_f[4][u][e] = alpha * sh0 * x1v[j][0];
            s_f[5][u][e] = alpha * sh0 * x1v[j][1];
            s_f[6][u][e] = alpha * sh0 * x1v[j][2];
            s_f[7][u][e] = ai3 * (x1v[j][0]*s1x + x1v[j][1]*s1y + x1v[j][2]*s1z);
        }
    }
    // ---- phase 0b: stage edge_attr into s_hb [e][132] ----
    for (int t = tid; t < EPB * (FDIM / 4); t += NTHR) {
        const int e = t >> 5, i4 = t & 31;
        const float4 v = ((const float4*)(edge_attr + (size_t)(e0 + e) * FDIM))[i4];
        *(float4*)&s_hb[e * 132 + i4 * 4] = v;
    }
    __syncthreads();   // B1: attr + factors + dst visible

    // ---- phase 1a: A1 fragments for ALL 64 edges (from staged attr) ----
    bf16x8 A1h[4][4], A1l[4][4];   // [g][ks]
    #pragma unroll
    for (int g = 0; g < 4; ++g)
        #pragma unroll
        for (int ks = 0; ks < 4; ++ks) {
            const float* hp = &s_hb[(g * 16 + li) * 132 + ks * 32 + quad * 8];
            const float4 f0 = *(const float4*)hp;
            const float4 f1 = *(const float4*)(hp + 4);
            const float fv[8] = {f0.x, f0.y, f0.z, f0.w, f1.x, f1.y, f1.z, f1.w};
            #pragma unroll
            for (int j = 0; j < 8; ++j) {
                const __bf16 h = (__bf16)fv[j];
                A1h[g][ks][j] = h;
                A1l[g][ks][j] = (__bf16)(fv[j] - (float)h);
            }
        }
    __syncthreads();   // B2: attr region dead; h writes may begin

    // ---- phase 1b: GEMM1 (wave w -> n-tiles 2w, 2w+1; B1 from L2) ----
    #pragma unroll
    for (int nt2 = 0; nt2 < 2; ++nt2) {
        const int nt = w * 2 + nt2;
        const float b1v = fc_b1[nt * 16 + li];
        f32x4 acc[4];
        #pragma unroll
        for (int g = 0; g < 4; ++g) acc[g] = (f32x4){b1v, b1v, b1v, b1v};
        #pragma unroll
        for (int ks = 0; ks < 4; ++ks) {
            const size_t fb = ((size_t)((nt * 4 + ks) * 2) * 64 + lane) * 8;
            const bf16x8 bh = *(const bf16x8*)(W1B + fb);
            const bf16x8 bl = *(const bf16x8*)(W1B + fb + 512);
            #pragma unroll
            for (int g = 0; g < 4; ++g) {
                acc[g] = MFMA16(A1h[g][ks], bh, acc[g]);
                acc[g] = MFMA16(A1h[g][ks], bl, acc[g]);
                acc[g] = MFMA16(A1l[g][ks], bh, acc[g]);
            }
        }
        #pragma unroll
        for (int g = 0; g < 4; ++g)
            #pragma unroll
            for (int r = 0; r < 4; ++r)
                s_hb[(g * 16 + quad * 4 + r) * 132 + nt * 16 + li] = fmaxf(acc[g][r], 0.f);
    }
    __syncthreads();   // B3: h complete

    // ---- phase 2: A2 fragments (this wave's K-half) for ALL 64 edges ----
    bf16x8 A2h[4][2], A2l[4][2];   // [g][k2], global ks = kh*2 + k2
    #pragma unroll
    for (int g = 0; g < 4; ++g)
        #pragma unroll
        for (int k2 = 0; k2 < 2; ++k2) {
            const float* hp = &s_hb[(g * 16 + li) * 132 + kh * 64 + k2 * 32 + quad * 8];
            const float4 f0 = *(const float4*)hp;
            const float4 f1 = *(const float4*)(hp + 4);
            const float fv[8] = {f0.x, f0.y, f0.z, f0.w, f1.x, f1.y, f1.z, f1.w};
            #pragma unroll
            for (int j = 0; j < 8; ++j) {
                const __bf16 h = (__bf16)fv[j];
                A2h[g][k2][j] = h;
                A2l[g][k2][j] = (__bf16)(fv[j] - (float)h);
            }
        }

    // ---- phase 3: GEMM2 + TP fold (no barriers; B dbuf in regs from L2) ----
    f32x4 o0[4];      // p0 (th=0) or p3 (th=1)
    f32x4 o1[4][3];   // p1 (th=0) or p2 (th=1)
    #pragma unroll
    for (int g = 0; g < 4; ++g) {
        o0[g] = (f32x4){0.f, 0.f, 0.f, 0.f};
        #pragma unroll
        for (int m = 0; m < 3; ++m) o1[g][m] = (f32x4){0.f, 0.f, 0.f, 0.f};
    }
    const int tbase = th * 32;
    bf16x8 nBh[2], nBl[2];
    #pragma unroll
    for (int k2 = 0; k2 < 2; ++k2) {   // preload tile c=0
        const size_t fb = ((size_t)((tbase * 4 + kh * 2 + k2) * 2) * 64 + lane) * 8;
        nBh[k2] = *(const bf16x8*)(W2B + fb);
        nBl[k2] = *(const bf16x8*)(W2B + fb + 512);
    }
    #pragma unroll
    for (int half = 0; half < 2; ++half) {
        #pragma unroll
        for (int cc = 0; cc < 16; ++cc) {
            const int c = half * 16 + cc;
            const int t = tbase + c;
            const int u = cc;
            const bf16x8 cBh[2] = {nBh[0], nBh[1]};
            const bf16x8 cBl[2] = {nBl[0], nBl[1]};
            if (c + 1 < 32) {
                const int tn = tbase + c + 1;
                #pragma unroll
                for (int k2 = 0; k2 < 2; ++k2) {
                    const size_t fb = ((size_t)((tn * 4 + kh * 2 + k2) * 2) * 64 + lane) * 8;
                    nBh[k2] = *(const bf16x8*)(W2B + fb);
                    nBl[k2] = *(const bf16x8*)(W2B + fb + 512);
                }
            }
            const float b2v = fc_b2[t * 16 + li];
            f32x4 acc[4];
            #pragma unroll
            for (int g = 0; g < 4; ++g) acc[g] = (f32x4){0.f, 0.f, 0.f, 0.f};
            #pragma unroll
            for (int k2 = 0; k2 < 2; ++k2)
                #pragma unroll
                for (int g = 0; g < 4; ++g) {
                    acc[g] = MFMA16(A2h[g][k2], cBh[k2], acc[g]);
                    acc[g] = MFMA16(A2h[g][k2], cBl[k2], acc[g]);
                    acc[g] = MFMA16(A2l[g][k2], cBh[k2], acc[g]);
                }
            if (kh == 0) {   // bias exactly once across K-halves
                #pragma unroll
                for (int g = 0; g < 4; ++g) {
                    acc[g][0] += b2v; acc[g][1] += b2v; acc[g][2] += b2v; acc[g][3] += b2v;
                }
            }
            // fold: p = th*2 + half, tile-constant; factor float4 covers this lane's 4 C-rows
            if (th == 0) {
                if (half == 0) {
                    #pragma unroll
                    for (int g = 0; g < 4; ++g) {
                        const f32x4 f = *(const f32x4*)&s_f[0][u][g * 16 + quad * 4];
                        o0[g] += f * acc[g];
                    }
                } else {
                    #pragma unroll
                    for (int g = 0; g < 4; ++g)
                        #pragma unroll
                        for (int m = 0; m < 3; ++m) {
                            const f32x4 f = *(const f32x4*)&s_f[1 + m][u][g * 16 + quad * 4];
                            o1[g][m] += f * acc[g];
                        }
                }
            } else {
                if (half == 0) {
                    #pragma unroll
                    for (int g = 0; g < 4; ++g)
                        #pragma unroll
                        for (int m = 0; m < 3; ++m) {
                            const f32x4 f = *(const f32x4*)&s_f[4 + m][u][g * 16 + quad * 4];
                            o1[g][m] += f * acc[g];
                        }
                } else {
                    #pragma unroll
                    for (int g = 0; g < 4; ++g) {
                        const f32x4 f = *(const f32x4*)&s_f[7][u][g * 16 + quad * 4];
                        o0[g] += f * acc[g];
                    }
                }
            }
        }
    }

    // ---- phase 4: kh-merge via LDS (s_f/s_hb dead), then scatter by kh==0 waves ----
    __syncthreads();   // B4
    float* red = s_hb;                    // [th][e][65] pad-65: 2*64*65*4 = 33280 B
    if (kh == 1) {
        float* rp = red + th * 64 * 65;
        #pragma unroll
        for (int g = 0; g < 4; ++g)
            #pragma unroll
            for (int r = 0; r < 4; ++r) {
                float* row = rp + (g * 16 + quad * 4 + r) * 65;
                row[li] = o0[g][r];
                #pragma unroll
                for (int m = 0; m < 3; ++m) row[16 + li * 3 + m] = o1[g][m][r];
            }
    }
    __syncthreads();   // B5
    if (kh == 0) {
        const float* rp = red + th * 64 * 65;
        #pragma unroll
        for (int g = 0; g < 4; ++g)
            #pragma unroll
            for (int r = 0; r < 4; ++r) {
                const int e = g * 16 + quad * 4 + r;
                const float* row = rp + e * 65;
                float* op = out_acc + (size_t)s_dst[e] * CDIM;
                unsafeAtomicAdd(&op[li], o0[g][r] + row[li]);
                #pragma unroll
                for (int m = 0; m < 3; ++m)
                    unsafeAtomicAdd(&op[16 + li * 3 + m], o1[g][m][r] + row[16 + li * 3 + m]);
            }
    }
}

__global__ void finalize_kernel(const float* __restrict__ x,
                                const int*   __restrict__ cnt,
                                float*       __restrict__ out)
{
    const int idx = blockIdx.x * blockDim.x + threadIdx.x;
    if (idx < NODES * CDIM) {
        const int n = idx >> 6;
        const float c = (float)(cnt[n] > 1 ? cnt[n] : 1);
        out[idx] = out[idx] / c + x[idx];
    }
}

extern "C" void kernel_launch(void* const* d_in, const int* in_sizes, int n_in,
                              void* d_out, int out_size, void* d_ws, size_t ws_size,
                              hipStream_t stream) {
    (void)in_sizes; (void)n_in; (void)out_size; (void)ws_size;
    const float* x          = (const float*)d_in[0];
    const int*   edge_index = (const int*)  d_in[1];
    const float* edge_attr  = (const float*)d_in[2];
    const float* edge_sh    = (const float*)d_in[3];
    const float* fc_w1      = (const float*)d_in[4];
    const float* fc_b1      = (const float*)d_in[5];
    const float* fc_w2      = (const float*)d_in[6];
    const float* fc_b2      = (const float*)d_in[7];
    float*  out = (float*)d_out;
    __bf16* W2B = (__bf16*)d_ws;
    __bf16* W1B = (__bf16*)((char*)d_ws + WS_W1B);
    int*    cnt = (int*)((char*)d_ws + WS_CNT);

    prep_kernel<<<80, NTHR, 0, stream>>>(fc_w1, fc_w2, W1B, W2B, out, cnt);
    fused_edge_kernel<<<E_TOTAL / EPB, NTHR, 0, stream>>>(
        x, edge_index, edge_attr, edge_sh, fc_b1, fc_b2, W1B, W2B, out, cnt);
    finalize_kernel<<<(NODES * CDIM + NTHR - 1) / NTHR, NTHR, 0, stream>>>(x, cnt, out);
}

// Round 4
// 372.978 us; speedup vs baseline: 3.5553x; 1.0108x over previous
//
#include <hip/hip_runtime.h>
#include <stdint.h>

#define E_TOTAL 160000
#define NODES   10000
#define FDIM    128
#define HDIM    128
#define WN      1024
#define CDIM    64
#define EPB     32
#define NTHR    256

typedef __bf16 bf16x8 __attribute__((ext_vector_type(8)));
typedef float  f32x4  __attribute__((ext_vector_type(4)));

#define MFMA16(a,b,c) __builtin_amdgcn_mfma_f32_16x16x32_bf16(a,b,c,0,0,0)

// ws layout: [0, 512K) W2B split-bf16 B-frags ; [512K, 576K) W1B ; [576K, +40K) cnt
#define WS_W1B (512*1024)
#define WS_CNT (576*1024)

// ---------- prep: split W1/W2 to bf16 hi/lo B-fragments + zero out/cnt ----------
// Fragment layout: [tile][ks][term][lane][8 bf16]; lane holds n = tile*16 + (lane&15),
// k = ks*32 + (lane>>4)*8 + j.  One 256-thr block per tile (4 ks x 64 lanes).
__global__ void prep_kernel(const float* __restrict__ W1, const float* __restrict__ W2,
                            __bf16* __restrict__ W1B, __bf16* __restrict__ W2B,
                            float* __restrict__ out_acc, int* __restrict__ cnt) {
    const int b   = blockIdx.x;
    const int tid = threadIdx.x;
    if (b < 72) {
        const float* W = (b < 64) ? W2 : W1;
        __bf16* outB   = (b < 64) ? W2B : W1B;
        const int N    = (b < 64) ? WN : HDIM;
        const int tile = (b < 64) ? b : (b - 64);
        const int lane = tid & 63;
        const int ks   = tid >> 6;
        const int n  = tile * 16 + (lane & 15);
        const int k0 = ks * 32 + (lane >> 4) * 8;
        bf16x8 hi, lo;
        #pragma unroll
        for (int j = 0; j < 8; ++j) {
            const float v = W[(size_t)(k0 + j) * N + n];
            const __bf16 h = (__bf16)v;
            hi[j] = h;
            lo[j] = (__bf16)(v - (float)h);
        }
        const size_t base = ((size_t)(tile * 4 + ks) * 2 * 64 + lane) * 8;
        *(bf16x8*)(outB + base)       = hi;
        *(bf16x8*)(outB + base + 512) = lo;
    } else {
        const int zt = (b - 72) * NTHR + tid;            // 8 blocks x 256 = 2048 threads
        const float4 z4 = make_float4(0.f, 0.f, 0.f, 0.f);
        for (int i = zt; i < NODES * CDIM / 4; i += 8 * NTHR) ((float4*)out_acc)[i] = z4;
        for (int i = zt; i < NODES; i += 8 * NTHR) cnt[i] = 0;
    }
}

// ---------- fused: gather + MLP + tensor product + scatter ----------
// Per block: 32 edges, 4 waves = (th = w>>1, kh = w&1):
//   GEMM2: wave covers tiles [th*32, th*32+32) x K-half [kh*64, kh*64+64) for ALL 32 edges.
//   K-partials legal (TP fold linear in acc); bias added by kh==0 only.
// Small footprint: 33 KB LDS + <=128 VGPR -> 4 blocks/CU, 4 waves/SIMD.
__global__ __launch_bounds__(NTHR, 4)
void fused_edge_kernel(const float* __restrict__ x,
                       const int*   __restrict__ edge_index,
                       const float* __restrict__ edge_attr,
                       const float* __restrict__ edge_sh,
                       const float* __restrict__ fc_b1,
                       const float* __restrict__ fc_b2,
                       const __bf16* __restrict__ W1B,
                       const __bf16* __restrict__ W2B,
                       float* __restrict__ out_acc,
                       int*   __restrict__ cnt)
{
    // fold factors [8][u][e]: 0:a*sh0*x0 (p0) | 1..3:a*x0*sh1_m (p1) | 4..6:a*sh0*x1_m (p2) | 7:a/sqrt3*dot (p3)
    __shared__ float s_f[8][16][EPB];                  // 16 KB
    __shared__ __align__(16) float s_hb[EPB * 132];    // 16.9 KB: attr -> h -> red (pad 132 == 4 mod 32)
    __shared__ int s_dst[EPB];

    const int tid  = threadIdx.x;
    const int w    = tid >> 6;
    const int th   = w >> 1;
    const int kh   = w & 1;
    const int lane = tid & 63;
    const int quad = lane >> 4;
    const int li   = lane & 15;
    const int e0   = blockIdx.x * EPB;

    // ---- phase 0a: geometry factors (wave w, lanes<32: u in [w*4, w*4+4) for 32 edges) ----
    if (lane < 32) {
        const int e  = lane;
        const int up = w * 4;
        const int ge = e0 + e;
        const int src = edge_index[ge];
        const float4 sh4 = *(const float4*)(edge_sh + (size_t)ge * 4);
        if (tid < EPB) {
            const int d = edge_index[E_TOTAL + ge];
            s_dst[e] = d;
            atomicAdd(&cnt[d], 1);
        }
        const float* xp = x + (size_t)src * CDIM;
        const float4 x0v = *(const float4*)(xp + up);
        const float4 xa  = *(const float4*)(xp + 16 + up * 3);
        const float4 xb  = *(const float4*)(xp + 16 + up * 3 + 4);
        const float4 xc  = *(const float4*)(xp + 16 + up * 3 + 8);
        const float x1v[4][3] = {
            {xa.x, xa.y, xa.z}, {xa.w, xb.x, xb.y},
            {xb.z, xb.w, xc.x}, {xc.y, xc.z, xc.w}};
        const float x0a[4] = {x0v.x, x0v.y, x0v.z, x0v.w};
        const float alpha = 0.17677669529663689f;           // 1/sqrt(2*MUL)
        const float ai3   = alpha * 0.57735026918962576f;   // alpha/sqrt(3)
        const float sh0 = sh4.x, s1x = sh4.y, s1y = sh4.z, s1z = sh4.w;
        #pragma unroll
        for (int j = 0; j < 4; ++j) {
            const int u = up + j;
            const float x0u = x0a[j];
            s_f[0][u][e] = alpha * sh0 * x0u;
            s_f[1][u][e] = alpha * x0u * s1x;
            s_f[2][u][e] = alpha * x0u * s1y;
            s_f[3][u][e] = alpha * x0u * s1z;
            s_f[4][u][e] = alpha * sh0 * x1v[j][0];
            s_f[5][u][e] = alpha * sh0 * x1v[j][1];
            s_f[6][u][e] = alpha * sh0 * x1v[j][2];
            s_f[7][u][e] = ai3 * (x1v[j][0]*s1x + x1v[j][1]*s1y + x1v[j][2]*s1z);
        }
    }
    // ---- phase 0b: stage edge_attr into s_hb [e][132] ----
    #pragma unroll
    for (int t4 = 0; t4 < 4; ++t4) {
        const int t = tid + t4 * NTHR;                 // EPB*32 float4 total
        const int e = t >> 5, i4 = t & 31;
        const float4 v = ((const float4*)(edge_attr + (size_t)(e0 + e) * FDIM))[i4];
        *(float4*)&s_hb[e * 132 + i4 * 4] = v;
    }
    __syncthreads();   // B1

    // ---- phase 1a: A1 fragments (32 edges = 2 g-tiles) ----
    bf16x8 A1h[2][4], A1l[2][4];
    #pragma unroll
    for (int g = 0; g < 2; ++g)
        #pragma unroll
        for (int ks = 0; ks < 4; ++ks) {
            const float* hp = &s_hb[(g * 16 + li) * 132 + ks * 32 + quad * 8];
            const float4 f0 = *(const float4*)hp;
            const float4 f1 = *(const float4*)(hp + 4);
            const float fv[8] = {f0.x, f0.y, f0.z, f0.w, f1.x, f1.y, f1.z, f1.w};
            #pragma unroll
            for (int j = 0; j < 8; ++j) {
                const __bf16 h = (__bf16)fv[j];
                A1h[g][ks][j] = h;
                A1l[g][ks][j] = (__bf16)(fv[j] - (float)h);
            }
        }
    __syncthreads();   // B2: attr region dead; h writes may begin

    // ---- phase 1b: GEMM1 (wave w -> n-tiles 2w, 2w+1) ----
    #pragma unroll
    for (int nt2 = 0; nt2 < 2; ++nt2) {
        const int nt = w * 2 + nt2;
        const float b1v = fc_b1[nt * 16 + li];
        f32x4 acc[2];
        #pragma unroll
        for (int g = 0; g < 2; ++g) acc[g] = (f32x4){b1v, b1v, b1v, b1v};
        #pragma unroll
        for (int ks = 0; ks < 4; ++ks) {
            const size_t fb = ((size_t)((nt * 4 + ks) * 2) * 64 + lane) * 8;
            const bf16x8 bh = *(const bf16x8*)(W1B + fb);
            const bf16x8 bl = *(const bf16x8*)(W1B + fb + 512);
            #pragma unroll
            for (int g = 0; g < 2; ++g) {
                acc[g] = MFMA16(A1h[g][ks], bh, acc[g]);
                acc[g] = MFMA16(A1h[g][ks], bl, acc[g]);
                acc[g] = MFMA16(A1l[g][ks], bh, acc[g]);
            }
        }
        #pragma unroll
        for (int g = 0; g < 2; ++g)
            #pragma unroll
            for (int r = 0; r < 4; ++r)
                s_hb[(g * 16 + quad * 4 + r) * 132 + nt * 16 + li] = fmaxf(acc[g][r], 0.f);
    }
    __syncthreads();   // B3: h complete

    // ---- phase 2: A2 fragments (this wave's K-half) ----
    bf16x8 A2h[2][2], A2l[2][2];   // [g][k2], global ks = kh*2 + k2
    #pragma unroll
    for (int g = 0; g < 2; ++g)
        #pragma unroll
        for (int k2 = 0; k2 < 2; ++k2) {
            const float* hp = &s_hb[(g * 16 + li) * 132 + kh * 64 + k2 * 32 + quad * 8];
            const float4 f0 = *(const float4*)hp;
            const float4 f1 = *(const float4*)(hp + 4);
            const float fv[8] = {f0.x, f0.y, f0.z, f0.w, f1.x, f1.y, f1.z, f1.w};
            #pragma unroll
            for (int j = 0; j < 8; ++j) {
                const __bf16 h = (__bf16)fv[j];
                A2h[g][k2][j] = h;
                A2l[g][k2][j] = (__bf16)(fv[j] - (float)h);
            }
        }

    // ---- phase 3: GEMM2 + TP fold (no barriers; B dbuf in regs) ----
    f32x4 o0[2];      // p0 (th=0) or p3 (th=1)
    f32x4 o1[2][3];   // p1 (th=0) or p2 (th=1)
    #pragma unroll
    for (int g = 0; g < 2; ++g) {
        o0[g] = (f32x4){0.f, 0.f, 0.f, 0.f};
        #pragma unroll
        for (int m = 0; m < 3; ++m) o1[g][m] = (f32x4){0.f, 0.f, 0.f, 0.f};
    }
    const int tbase = th * 32;
    bf16x8 nBh[2], nBl[2];
    #pragma unroll
    for (int k2 = 0; k2 < 2; ++k2) {   // preload tile c=0
        const size_t fb = ((size_t)((tbase * 4 + kh * 2 + k2) * 2) * 64 + lane) * 8;
        nBh[k2] = *(const bf16x8*)(W2B + fb);
        nBl[k2] = *(const bf16x8*)(W2B + fb + 512);
    }
    #pragma unroll
    for (int half = 0; half < 2; ++half) {
        #pragma unroll
        for (int cc = 0; cc < 16; ++cc) {
            const int c = half * 16 + cc;
            const int t = tbase + c;
            const int u = cc;
            const bf16x8 cBh[2] = {nBh[0], nBh[1]};
            const bf16x8 cBl[2] = {nBl[0], nBl[1]};
            if (c + 1 < 32) {
                const int tn = tbase + c + 1;
                #pragma unroll
                for (int k2 = 0; k2 < 2; ++k2) {
                    const size_t fb = ((size_t)((tn * 4 + kh * 2 + k2) * 2) * 64 + lane) * 8;
                    nBh[k2] = *(const bf16x8*)(W2B + fb);
                    nBl[k2] = *(const bf16x8*)(W2B + fb + 512);
                }
            }
            const float b2v = fc_b2[t * 16 + li];
            f32x4 acc[2];
            #pragma unroll
            for (int g = 0; g < 2; ++g) acc[g] = (f32x4){0.f, 0.f, 0.f, 0.f};
            #pragma unroll
            for (int k2 = 0; k2 < 2; ++k2)
                #pragma unroll
                for (int g = 0; g < 2; ++g) {
                    acc[g] = MFMA16(A2h[g][k2], cBh[k2], acc[g]);
                    acc[g] = MFMA16(A2h[g][k2], cBl[k2], acc[g]);
                    acc[g] = MFMA16(A2l[g][k2], cBh[k2], acc[g]);
                }
            if (kh == 0) {
                #pragma unroll
                for (int g = 0; g < 2; ++g) {
                    acc[g][0] += b2v; acc[g][1] += b2v; acc[g][2] += b2v; acc[g][3] += b2v;
                }
            }
            // fold: p = th*2 + half (tile-constant); factor float4 covers this lane's 4 C-rows
            if (th == 0) {
                if (half == 0) {
                    #pragma unroll
                    for (int g = 0; g < 2; ++g) {
                        const f32x4 f = *(const f32x4*)&s_f[0][u][g * 16 + quad * 4];
                        o0[g] += f * acc[g];
                    }
                } else {
                    #pragma unroll
                    for (int g = 0; g < 2; ++g)
                        #pragma unroll
                        for (int m = 0; m < 3; ++m) {
                            const f32x4 f = *(const f32x4*)&s_f[1 + m][u][g * 16 + quad * 4];
                            o1[g][m] += f * acc[g];
                        }
                }
            } else {
                if (half == 0) {
                    #pragma unroll
                    for (int g = 0; g < 2; ++g)
                        #pragma unroll
                        for (int m = 0; m < 3; ++m) {
                            const f32x4 f = *(const f32x4*)&s_f[4 + m][u][g * 16 + quad * 4];
                            o1[g][m] += f * acc[g];
                        }
                } else {
                    #pragma unroll
                    for (int g = 0; g < 2; ++g) {
                        const f32x4 f = *(const f32x4*)&s_f[7][u][g * 16 + quad * 4];
                        o0[g] += f * acc[g];
                    }
                }
            }
        }
    }

    // ---- phase 4: kh-merge via LDS (s_hb dead), then scatter by kh==0 waves ----
    __syncthreads();   // B4
    float* red = s_hb;                    // [th][e][65]: 2*32*65*4 = 16640 B <= 16896
    if (kh == 1) {
        float* rp = red + th * 32 * 65;
        #pragma unroll
        for (int g = 0; g < 2; ++g)
            #pragma unroll
            for (int r = 0; r < 4; ++r) {
                float* row = rp + (g * 16 + quad * 4 + r) * 65;
                row[li] = o0[g][r];
                #pragma unroll
                for (int m = 0; m < 3; ++m) row[16 + li * 3 + m] = o1[g][m][r];
            }
    }
    __syncthreads();   // B5
    if (kh == 0) {
        const float* rp = red + th * 32 * 65;
        #pragma unroll
        for (int g = 0; g < 2; ++g)
            #pragma unroll
            for (int r = 0; r < 4; ++r) {
                const int e = g * 16 + quad * 4 + r;
                const float* row = rp + e * 65;
                float* op = out_acc + (size_t)s_dst[e] * CDIM;
                unsafeAtomicAdd(&op[li], o0[g][r] + row[li]);
                #pragma unroll
                for (int m = 0; m < 3; ++m)
                    unsafeAtomicAdd(&op[16 + li * 3 + m], o1[g][m][r] + row[16 + li * 3 + m]);
            }
    }
}

__global__ void finalize_kernel(const float* __restrict__ x,
                                const int*   __restrict__ cnt,
                                float*       __restrict__ out)
{
    const int idx = blockIdx.x * blockDim.x + threadIdx.x;
    if (idx < NODES * CDIM) {
        const int n = idx >> 6;
        const float c = (float)(cnt[n] > 1 ? cnt[n] : 1);
        out[idx] = out[idx] / c + x[idx];
    }
}

extern "C" void kernel_launch(void* const* d_in, const int* in_sizes, int n_in,
                              void* d_out, int out_size, void* d_ws, size_t ws_size,
                              hipStream_t stream) {
    (void)in_sizes; (void)n_in; (void)out_size; (void)ws_size;
    const float* x          = (const float*)d_in[0];
    const int*   edge_index = (const int*)  d_in[1];
    const float* edge_attr  = (const float*)d_in[2];
    const float* edge_sh    = (const float*)d_in[3];
    const float* fc_w1      = (const float*)d_in[4];
    const float* fc_b1      = (const float*)d_in[5];
    const float* fc_w2      = (const float*)d_in[6];
    const float* fc_b2      = (const float*)d_in[7];
    float*  out = (float*)d_out;
    __bf16* W2B = (__bf16*)d_ws;
    __bf16* W1B = (__bf16*)((char*)d_ws + WS_W1B);
    int*    cnt = (int*)((char*)d_ws + WS_CNT);

    prep_kernel<<<80, NTHR, 0, stream>>>(fc_w1, fc_w2, W1B, W2B, out, cnt);
    fused_edge_kernel<<<E_TOTAL / EPB, NTHR, 0, stream>>>(
        x, edge_index, edge_attr, edge_sh, fc_b1, fc_b2, W1B, W2B, out, cnt);
    finalize_kernel<<<(NODES * CDIM + NTHR - 1) / NTHR, NTHR, 0, stream>>>(x, cnt, out);
}

// Round 5
// 280.712 us; speedup vs baseline: 4.7238x; 1.3287x over previous
//
#include <hip/hip_runtime.h>
#include <stdint.h>

#define E_TOTAL 160000
#define NODES   10000
#define FDIM    128
#define HDIM    128
#define WN      1024
#define CDIM    64
#define EPB     32
#define NTHR    256

typedef __bf16 bf16x8 __attribute__((ext_vector_type(8)));
typedef float  f32x4  __attribute__((ext_vector_type(4)));

#define MFMA16(a,b,c) __builtin_amdgcn_mfma_f32_16x16x32_bf16(a,b,c,0,0,0)

// ws layout: [0, 256K) W2B hi-only B-frags ; [512K, 576K) W1B (hi+lo) ; [576K, +40K) cnt
#define WS_W1B (512*1024)
#define WS_CNT (576*1024)

__device__ __forceinline__ f32x4 ntload4(const float* p) {
    return __builtin_nontemporal_load((const f32x4*)p);
}

// ---------- prep ----------
// W2B (hi only): [tile][ks][lane][8 bf16], 1KB per (tile,ks); lane: n = tile*16+(lane&15),
// k = ks*32+(lane>>4)*8+j.   W1B (hi+lo): [tile][ks][term][lane][8].
__global__ void prep_kernel(const float* __restrict__ W1, const float* __restrict__ W2,
                            __bf16* __restrict__ W1B, __bf16* __restrict__ W2B,
                            float* __restrict__ out_acc, int* __restrict__ cnt) {
    const int b   = blockIdx.x;
    const int tid = threadIdx.x;
    if (b < 64) {                        // W2 tile b -> hi only
        const int lane = tid & 63, ks = tid >> 6;
        const int n  = b * 16 + (lane & 15);
        const int k0 = ks * 32 + (lane >> 4) * 8;
        bf16x8 hi;
        #pragma unroll
        for (int j = 0; j < 8; ++j) hi[j] = (__bf16)W2[(size_t)(k0 + j) * WN + n];
        *(bf16x8*)(W2B + ((size_t)(b * 4 + ks) * 64 + lane) * 8) = hi;
    } else if (b < 72) {                 // W1 tile (b-64) -> hi+lo
        const int tile = b - 64;
        const int lane = tid & 63, ks = tid >> 6;
        const int n  = tile * 16 + (lane & 15);
        const int k0 = ks * 32 + (lane >> 4) * 8;
        bf16x8 hi, lo;
        #pragma unroll
        for (int j = 0; j < 8; ++j) {
            const float v = W1[(size_t)(k0 + j) * HDIM + n];
            const __bf16 h = (__bf16)v;
            hi[j] = h;
            lo[j] = (__bf16)(v - (float)h);
        }
        const size_t base = ((size_t)(tile * 4 + ks) * 2 * 64 + lane) * 8;
        *(bf16x8*)(W1B + base)       = hi;
        *(bf16x8*)(W1B + base + 512) = lo;
    } else {
        const int zt = (b - 72) * NTHR + tid;
        const float4 z4 = make_float4(0.f, 0.f, 0.f, 0.f);
        for (int i = zt; i < NODES * CDIM / 4; i += 8 * NTHR) ((float4*)out_acc)[i] = z4;
        for (int i = zt; i < NODES; i += 8 * NTHR) cnt[i] = 0;
    }
}

// ---------- fused: gather + MLP + tensor product + scatter ----------
// Per block: 32 edges, 4 waves = (th = w>>1, kh = w&1). GEMM2: wave covers tiles
// [th*32, th*32+32) x K-half [kh*64,...) for all 32 edges; K/th partials merged in LDS;
// ONE wave scatters (1 atomic per output element per edge).
__global__ __launch_bounds__(NTHR, 4)
void fused_edge_kernel(const float* __restrict__ x,
                       const int*   __restrict__ edge_index,
                       const float* __restrict__ edge_attr,
                       const float* __restrict__ edge_sh,
                       const float* __restrict__ fc_b1,
                       const float* __restrict__ fc_b2,
                       const __bf16* __restrict__ W1B,
                       const __bf16* __restrict__ W2B,
                       float* __restrict__ out_acc,
                       int*   __restrict__ cnt)
{
    // fold factors [8][u][e]: 0:a*sh0*x0 (p0) | 1..3:a*x0*sh1_m (p1) | 4..6:a*sh0*x1_m (p2) | 7:a/sqrt3*dot (p3)
    __shared__ float s_f[8][16][EPB];                  // 16 KB ; reused as dump region C
    __shared__ __align__(16) float s_hb[EPB * 132];    // 16.9 KB: attr -> h -> dump A/B
    __shared__ int s_dst[EPB];

    const int tid  = threadIdx.x;
    const int w    = tid >> 6;
    const int th   = w >> 1;
    const int kh   = w & 1;
    const int lane = tid & 63;
    const int quad = lane >> 4;
    const int li   = lane & 15;
    const int e0   = blockIdx.x * EPB;

    // ---- phase 0a: geometry factors (wave w, lanes<32: u in [w*4, w*4+4)) ----
    if (lane < 32) {
        const int e  = lane;
        const int up = w * 4;
        const int ge = e0 + e;
        const int src = edge_index[ge];
        const f32x4 sh4 = ntload4(edge_sh + (size_t)ge * 4);
        if (tid < EPB) {
            const int d = edge_index[E_TOTAL + ge];
            s_dst[e] = d;
            atomicAdd(&cnt[d], 1);
        }
        const float* xp = x + (size_t)src * CDIM;
        const float4 x0v = *(const float4*)(xp + up);
        const float4 xa  = *(const float4*)(xp + 16 + up * 3);
        const float4 xb  = *(const float4*)(xp + 16 + up * 3 + 4);
        const float4 xc  = *(const float4*)(xp + 16 + up * 3 + 8);
        const float x1v[4][3] = {
            {xa.x, xa.y, xa.z}, {xa.w, xb.x, xb.y},
            {xb.z, xb.w, xc.x}, {xc.y, xc.z, xc.w}};
        const float x0a[4] = {x0v.x, x0v.y, x0v.z, x0v.w};
        const float alpha = 0.17677669529663689f;           // 1/sqrt(2*MUL)
        const float ai3   = alpha * 0.57735026918962576f;   // alpha/sqrt(3)
        const float sh0 = sh4.x, s1x = sh4.y, s1y = sh4.z, s1z = sh4.w;
        #pragma unroll
        for (int j = 0; j < 4; ++j) {
            const int u = up + j;
            const float x0u = x0a[j];
            s_f[0][u][e] = alpha * sh0 * x0u;
            s_f[1][u][e] = alpha * x0u * s1x;
            s_f[2][u][e] = alpha * x0u * s1y;
            s_f[3][u][e] = alpha * x0u * s1z;
            s_f[4][u][e] = alpha * sh0 * x1v[j][0];
            s_f[5][u][e] = alpha * sh0 * x1v[j][1];
            s_f[6][u][e] = alpha * sh0 * x1v[j][2];
            s_f[7][u][e] = ai3 * (x1v[j][0]*s1x + x1v[j][1]*s1y + x1v[j][2]*s1z);
        }
    }
    // ---- phase 0b: stage edge_attr into s_hb [e][132] (non-temporal stream) ----
    #pragma unroll
    for (int t4 = 0; t4 < 4; ++t4) {
        const int t = tid + t4 * NTHR;                 // EPB*32 float4 total
        const int e = t >> 5, i4 = t & 31;
        const f32x4 v = ntload4(edge_attr + (size_t)(e0 + e) * FDIM + i4 * 4);
        *(f32x4*)&s_hb[e * 132 + i4 * 4] = v;
    }
    __syncthreads();   // B1

    // ---- phase 1a: A1 fragments (32 edges = 2 g-tiles) ----
    bf16x8 A1h[2][4], A1l[2][4];
    #pragma unroll
    for (int g = 0; g < 2; ++g)
        #pragma unroll
        for (int ks = 0; ks < 4; ++ks) {
            const float* hp = &s_hb[(g * 16 + li) * 132 + ks * 32 + quad * 8];
            const float4 f0 = *(const float4*)hp;
            const float4 f1 = *(const float4*)(hp + 4);
            const float fv[8] = {f0.x, f0.y, f0.z, f0.w, f1.x, f1.y, f1.z, f1.w};
            #pragma unroll
            for (int j = 0; j < 8; ++j) {
                const __bf16 h = (__bf16)fv[j];
                A1h[g][ks][j] = h;
                A1l[g][ks][j] = (__bf16)(fv[j] - (float)h);
            }
        }
    __syncthreads();   // B2: attr region dead; h writes may begin

    // ---- phase 1b: GEMM1 (wave w -> n-tiles 2w, 2w+1; 3-term) ----
    #pragma unroll
    for (int nt2 = 0; nt2 < 2; ++nt2) {
        const int nt = w * 2 + nt2;
        const float b1v = fc_b1[nt * 16 + li];
        f32x4 acc[2];
        #pragma unroll
        for (int g = 0; g < 2; ++g) acc[g] = (f32x4){b1v, b1v, b1v, b1v};
        #pragma unroll
        for (int ks = 0; ks < 4; ++ks) {
            const size_t fb = ((size_t)((nt * 4 + ks) * 2) * 64 + lane) * 8;
            const bf16x8 bh = *(const bf16x8*)(W1B + fb);
            const bf16x8 bl = *(const bf16x8*)(W1B + fb + 512);
            #pragma unroll
            for (int g = 0; g < 2; ++g) {
                acc[g] = MFMA16(A1h[g][ks], bh, acc[g]);
                acc[g] = MFMA16(A1h[g][ks], bl, acc[g]);
                acc[g] = MFMA16(A1l[g][ks], bh, acc[g]);
            }
        }
        #pragma unroll
        for (int g = 0; g < 2; ++g)
            #pragma unroll
            for (int r = 0; r < 4; ++r)
                s_hb[(g * 16 + quad * 4 + r) * 132 + nt * 16 + li] = fmaxf(acc[g][r], 0.f);
    }
    __syncthreads();   // B3: h complete

    // ---- phase 2: A2 fragments (this wave's K-half), h split hi+lo ----
    bf16x8 A2h[2][2], A2l[2][2];   // [g][k2], global ks = kh*2 + k2
    #pragma unroll
    for (int g = 0; g < 2; ++g)
        #pragma unroll
        for (int k2 = 0; k2 < 2; ++k2) {
            const float* hp = &s_hb[(g * 16 + li) * 132 + kh * 64 + k2 * 32 + quad * 8];
            const float4 f0 = *(const float4*)hp;
            const float4 f1 = *(const float4*)(hp + 4);
            const float fv[8] = {f0.x, f0.y, f0.z, f0.w, f1.x, f1.y, f1.z, f1.w};
            #pragma unroll
            for (int j = 0; j < 8; ++j) {
                const __bf16 h = (__bf16)fv[j];
                A2h[g][k2][j] = h;
                A2l[g][k2][j] = (__bf16)(fv[j] - (float)h);
            }
        }

    // ---- phase 3: GEMM2 (2-term: Ah*Bh + Al*Bh) + TP fold; depth-2 B prefetch ----
    f32x4 o0[2];      // p0 (th=0) or p3 (th=1)
    f32x4 o1[2][3];   // p1 (th=0) or p2 (th=1)
    #pragma unroll
    for (int g = 0; g < 2; ++g) {
        o0[g] = (f32x4){0.f, 0.f, 0.f, 0.f};
        #pragma unroll
        for (int m = 0; m < 3; ++m) o1[g][m] = (f32x4){0.f, 0.f, 0.f, 0.f};
    }
    const int tbase = th * 32;
    bf16x8 P[2][2];   // [stage][k2]
    #pragma unroll
    for (int s = 0; s < 2; ++s)
        #pragma unroll
        for (int k2 = 0; k2 < 2; ++k2)
            P[s][k2] = *(const bf16x8*)(W2B + ((size_t)((tbase + s) * 4 + kh * 2 + k2) * 64 + lane) * 8);

    #pragma unroll
    for (int half = 0; half < 2; ++half) {
        #pragma unroll
        for (int cc = 0; cc < 16; ++cc) {
            const int c = half * 16 + cc;
            const int t = tbase + c;
            const int u = cc;
            const bf16x8 b0 = P[c & 1][0];
            const bf16x8 b1 = P[c & 1][1];
            if (c + 2 < 32) {
                #pragma unroll
                for (int k2 = 0; k2 < 2; ++k2)
                    P[c & 1][k2] = *(const bf16x8*)(W2B + ((size_t)((t + 2) * 4 + kh * 2 + k2) * 64 + lane) * 8);
            }
            const float b2v = fc_b2[t * 16 + li];
            f32x4 acc[2];
            #pragma unroll
            for (int g = 0; g < 2; ++g) acc[g] = (f32x4){0.f, 0.f, 0.f, 0.f};
            #pragma unroll
            for (int g = 0; g < 2; ++g) {
                acc[g] = MFMA16(A2h[g][0], b0, acc[g]);
                acc[g] = MFMA16(A2l[g][0], b0, acc[g]);
                acc[g] = MFMA16(A2h[g][1], b1, acc[g]);
                acc[g] = MFMA16(A2l[g][1], b1, acc[g]);
            }
            if (kh == 0) {
                #pragma unroll
                for (int g = 0; g < 2; ++g) {
                    acc[g][0] += b2v; acc[g][1] += b2v; acc[g][2] += b2v; acc[g][3] += b2v;
                }
            }
            // fold: p = th*2 + half (tile-constant)
            if (th == 0) {
                if (half == 0) {
                    #pragma unroll
                    for (int g = 0; g < 2; ++g) {
                        const f32x4 f = *(const f32x4*)&s_f[0][u][g * 16 + quad * 4];
                        o0[g] += f * acc[g];
                    }
                } else {
                    #pragma unroll
                    for (int g = 0; g < 2; ++g)
                        #pragma unroll
                        for (int m = 0; m < 3; ++m) {
                            const f32x4 f = *(const f32x4*)&s_f[1 + m][u][g * 16 + quad * 4];
                            o1[g][m] += f * acc[g];
                        }
                }
            } else {
                if (half == 0) {
                    #pragma unroll
                    for (int g = 0; g < 2; ++g)
                        #pragma unroll
                        for (int m = 0; m < 3; ++m) {
                            const f32x4 f = *(const f32x4*)&s_f[4 + m][u][g * 16 + quad * 4];
                            o1[g][m] += f * acc[g];
                        }
                } else {
                    #pragma unroll
                    for (int g = 0; g < 2; ++g) {
                        const f32x4 f = *(const f32x4*)&s_f[7][u][g * 16 + quad * 4];
                        o0[g] += f * acc[g];
                    }
                }
            }
        }
    }

    // ---- phase 4: merge ALL partials in LDS; single wave scatters (1 atomic/elem) ----
    __syncthreads();   // B4: all phase-3 LDS reads done; s_f & s_hb reusable
    float* regA = s_hb;               // kh1,th0 dump: [e][65]
    float* regB = s_hb + 32 * 65;     // kh1,th1
    float* regC = (float*)s_f;        // kh0,th1
    float* dump = (kh == 1) ? ((th == 0) ? regA : regB) : ((th == 1) ? regC : nullptr);
    if (dump) {
        #pragma unroll
        for (int g = 0; g < 2; ++g)
            #pragma unroll
            for (int r = 0; r < 4; ++r) {
                float* row = dump + (g * 16 + quad * 4 + r) * 65;
                row[li] = o0[g][r];
                #pragma unroll
                for (int m = 0; m < 3; ++m) row[16 + li * 3 + m] = o1[g][m][r];
            }
    }
    __syncthreads();   // B5
    if (kh == 0 && th == 0) {
        #pragma unroll
        for (int g = 0; g < 2; ++g)
            #pragma unroll
            for (int r = 0; r < 4; ++r) {
                const int e = g * 16 + quad * 4 + r;
                const float* rA = regA + e * 65;
                const float* rB = regB + e * 65;
                const float* rC = regC + e * 65;
                float* op = out_acc + (size_t)s_dst[e] * CDIM;
                unsafeAtomicAdd(&op[li], o0[g][r] + rA[li] + rB[li] + rC[li]);
                #pragma unroll
                for (int m = 0; m < 3; ++m) {
                    const int s = 16 + li * 3 + m;
                    unsafeAtomicAdd(&op[s], o1[g][m][r] + rA[s] + rB[s] + rC[s]);
                }
            }
    }
}

__global__ void finalize_kernel(const float* __restrict__ x,
                                const int*   __restrict__ cnt,
                                float*       __restrict__ out)
{
    const int idx = blockIdx.x * blockDim.x + threadIdx.x;
    if (idx < NODES * CDIM) {
        const int n = idx >> 6;
        const float c = (float)(cnt[n] > 1 ? cnt[n] : 1);
        out[idx] = out[idx] / c + x[idx];
    }
}

extern "C" void kernel_launch(void* const* d_in, const int* in_sizes, int n_in,
                              void* d_out, int out_size, void* d_ws, size_t ws_size,
                              hipStream_t stream) {
    (void)in_sizes; (void)n_in; (void)out_size; (void)ws_size;
    const float* x          = (const float*)d_in[0];
    const int*   edge_index = (const int*)  d_in[1];
    const float* edge_attr  = (const float*)d_in[2];
    const float* edge_sh    = (const float*)d_in[3];
    const float* fc_w1      = (const float*)d_in[4];
    const float* fc_b1      = (const float*)d_in[5];
    const float* fc_w2      = (const float*)d_in[6];
    const float* fc_b2      = (const float*)d_in[7];
    float*  out = (float*)d_out;
    __bf16* W2B = (__bf16*)d_ws;
    __bf16* W1B = (__bf16*)((char*)d_ws + WS_W1B);
    int*    cnt = (int*)((char*)d_ws + WS_CNT);

    prep_kernel<<<80, NTHR, 0, stream>>>(fc_w1, fc_w2, W1B, W2B, out, cnt);
    fused_edge_kernel<<<E_TOTAL / EPB, NTHR, 0, stream>>>(
        x, edge_index, edge_attr, edge_sh, fc_b1, fc_b2, W1B, W2B, out, cnt);
    finalize_kernel<<<(NODES * CDIM + NTHR - 1) / NTHR, NTHR, 0, stream>>>(x, cnt, out);
}